// Round 10
// baseline (289.817 us; speedup 1.0000x reference)
//
#include <hip/hip_runtime.h>
#include <hip/hip_fp16.h>
#include <math.h>

#define NGAUSS 50
#define NF 64
#define DIM 128

#define GSTEP (10.0f/49.0f)
#define GCOEFF (-0.5f/(GSTEP*GSTEP))
#define INV_STEP (49.0f/10.0f)
#define EM1 0.36787944117144233f
#define PIC (3.14159265358979323846f/10.0f)
#define LOG2F_ 0.69314718055994530942f

typedef short v8s __attribute__((ext_vector_type(8)));
typedef _Float16 v8h __attribute__((ext_vector_type(8)));
typedef float v4f __attribute__((ext_vector_type(4)));
typedef unsigned short ushort_t;

#define MFMA(a,b,c)  __builtin_amdgcn_mfma_f32_16x16x32_bf16(a, b, c, 0, 0, 0)
#define MFMAH(a,b,c) __builtin_amdgcn_mfma_f32_16x16x32_f16(a, b, c, 0, 0, 0)
#define WAVE_BAR() __builtin_amdgcn_wave_barrier()

__device__ __forceinline__ unsigned short f2bf(float f) {
    unsigned u = __builtin_bit_cast(unsigned, f);
    unsigned r = (u + 0x7FFFu + ((u >> 16) & 1u)) >> 16;   // RNE
    return (unsigned short)r;
}
__device__ __forceinline__ unsigned cvt_pk_bf16(float lo, float hi) {
    unsigned r;
    asm("v_cvt_pk_bf16_f32 %0, %1, %2" : "=v"(r) : "v"(lo), "v"(hi));
    return r;
}
__device__ __forceinline__ unsigned short f2h(float f) {
    _Float16 h = (_Float16)f;                              // v_cvt_f16_f32
    return __builtin_bit_cast(unsigned short, h);
}
__device__ __forceinline__ float ssp_f(float x) {
    return fmaxf(x, 0.0f) + __logf(1.0f + __expf(-fabsf(x))) - LOG2F_;
}

// ---------- prep: weights -> bf16 (w2c -> f16), transposed to [col][k] ----------
extern "C" __global__ __launch_bounds__(256)
void k_prep(const float* __restrict__ w1, const float* __restrict__ w2,
            const float* __restrict__ cl1, const float* __restrict__ w2c,
            const float* __restrict__ wi, const float* __restrict__ wl,
            ushort_t* __restrict__ w1T, ushort_t* __restrict__ w2T,
            ushort_t* __restrict__ cl1T, ushort_t* __restrict__ w2cT,
            ushort_t* __restrict__ wiT, ushort_t* __restrict__ wlT)
{
    int id = blockIdx.x * 256 + threadIdx.x;
    int stride = gridDim.x * 256;
    for (int i = id; i < 64*64;   i += stride){ int c=i>>6, k=i&63;  w1T[i]  = f2bf(k < NGAUSS ? w1[k*64+c] : 0.0f); }
    for (int i = id; i < 64*64;   i += stride){ int c=i>>6, k=i&63;  w2T[i]  = f2bf(w2[k*64+c]); }
    for (int i = id; i < 64*128;  i += stride){ int c=i>>7, k=i&127; cl1T[i] = f2bf(cl1[k*64+c]); }
    for (int i = id; i < 128*64;  i += stride){ int c=i>>6, k=i&63;  w2cT[i] = f2h(w2c[k*128+c]); }   // f16 (pairs with f16 agg)
    for (int i = id; i < 128*128; i += stride){ int c=i>>7, k=i&127; wiT[i]  = f2bf(wi[k*128+c]); }
    for (int i = id; i < 128*128; i += stride){ int c=i>>7, k=i&127; wlT[i]  = f2bf(wl[k*128+c]); }
}

// ---------- h = x @ conv_lin1_w -> f16, MFMA, wave = 32 rows ----------
// Also zeroes agg (f16) for this block's rows.
extern "C" __global__ __launch_bounds__(256)
void k_lin1_mfma(const float* __restrict__ x, const ushort_t* __restrict__ cl1T,
                 ushort_t* __restrict__ h16, ushort_t* __restrict__ agg16, int N)
{
    {
        int nb = blockIdx.x * 128;
        int rows = min(128, N - nb);
        if (rows > 0) {
            float4* ap = (float4*)(agg16 + (size_t)nb * NF);
            int tot = rows * (NF * 2 / 16);       // rows * 8 float4s
            for (int i = threadIdx.x; i < tot; i += 256)
                ap[i] = (float4){0,0,0,0};
        }
    }

    int l = threadIdx.x & 63, w = threadIdx.x >> 6;
    int base = (blockIdx.x * 4 + w) * 32;
    int colb = l & 15, krow = (l >> 4) * 8;

    v4f C[2][4];
    #pragma unroll
    for (int m = 0; m < 2; m++)
        #pragma unroll
        for (int n = 0; n < 4; n++) C[m][n] = (v4f){0,0,0,0};

    #pragma unroll
    for (int kt = 0; kt < 4; kt++) {
        v8s am[2];
        #pragma unroll
        for (int m = 0; m < 2; m++) {
            int row = base + m*16 + colb;
            union { v8s v; unsigned d[4]; } A;
            A.d[0]=0; A.d[1]=0; A.d[2]=0; A.d[3]=0;
            if (row < N) {
                const float4* p = (const float4*)(x + (size_t)row*DIM + kt*32 + krow);
                float4 f0 = p[0], f1 = p[1];
                A.d[0] = cvt_pk_bf16(f0.x, f0.y);
                A.d[1] = cvt_pk_bf16(f0.z, f0.w);
                A.d[2] = cvt_pk_bf16(f1.x, f1.y);
                A.d[3] = cvt_pk_bf16(f1.z, f1.w);
            }
            am[m] = A.v;
        }
        #pragma unroll
        for (int n = 0; n < 4; n++) {
            v8s b = *(const v8s*)(cl1T + (n*16 + colb)*DIM + kt*32 + krow);
            #pragma unroll
            for (int m = 0; m < 2; m++) C[m][n] = MFMA(am[m], b, C[m][n]);
        }
    }
    #pragma unroll
    for (int m = 0; m < 2; m++)
        #pragma unroll
        for (int n = 0; n < 4; n++)
            #pragma unroll
            for (int i = 0; i < 4; i++) {
                int row = base + m*16 + (l>>4)*4 + i;
                if (row < N) h16[(size_t)row*NF + n*16 + colb] = f2h(C[m][n][i]);
            }
}

// ---------- edge kernel: MFMA MLP + split-phase packed-f16 atomic scatter ----------
extern "C" __global__ __launch_bounds__(256)
void k_edge_mfma(const float* __restrict__ pos, const int* __restrict__ ei,
                 const ushort_t* __restrict__ h16,
                 const ushort_t* __restrict__ w1T, const ushort_t* __restrict__ w2T,
                 const float* __restrict__ b1, const float* __restrict__ b2,
                 ushort_t* __restrict__ agg16, int E)
{
    __shared__ __align__(16) char lds[4][64*128];   // per-wave 64x64 x16bit, XOR-swizzled
    int l = threadIdx.x & 63, w = threadIdx.x >> 6;
    char* T = lds[w];
    size_t ebase = ((size_t)blockIdx.x * 4 + w) * 64;
    int e = (int)(ebase + l);
    bool valid = e < E;
    int s = valid ? ei[e] : 0;
    int d = valid ? ei[E + e] : 0;

    float dx = pos[3*d]   - pos[3*s];
    float dy = pos[3*d+1] - pos[3*s+1];
    float dz = pos[3*d+2] - pos[3*s+2];
    float dist = sqrtf(dx*dx + dy*dy + dz*dz);
    float Cc = valid ? 0.5f * (__cosf(dist * PIC) + 1.0f) : 0.0f;

    int colb = l & 15, krow = (l >> 4) * 8;

    float b1v[4], b2v[4];
    #pragma unroll
    for (int n = 0; n < 4; n++) { b1v[n] = b1[n*16 + colb]; b2v[n] = b2[n*16 + colb]; }

    // layer 1: ea (chain-exp, built directly in A-frag layout) @ w1
    v4f C1[4][4];
    #pragma unroll
    for (int m = 0; m < 4; m++)
        #pragma unroll
        for (int n = 0; n < 4; n++) C1[m][n] = (v4f){0,0,0,0};
    {
        v8s B1[2][4];
        #pragma unroll
        for (int n = 0; n < 4; n++)
            #pragma unroll
            for (int kt = 0; kt < 2; kt++)
                B1[kt][n] = *(const v8s*)(w1T + (n*16 + colb)*64 + kt*32 + krow);

        #pragma unroll
        for (int m = 0; m < 4; m++) {
            float dm = __shfl(dist, m*16 + colb);
            #pragma unroll
            for (int kt = 0; kt < 2; kt++) {
                int m0 = kt*32 + krow;
                float t0 = dm - (float)m0 * GSTEP;
                float e0 = __expf(GCOEFF * t0 * t0);
                float u  = __expf(fmaf(dm, INV_STEP, -((float)m0 + 0.5f)));
                float e1 = e0 * u; u *= EM1;
                float e2 = e1 * u; u *= EM1;
                float e3 = e2 * u; u *= EM1;
                float e4 = e3 * u; u *= EM1;
                float e5 = e4 * u; u *= EM1;
                float e6 = e5 * u; u *= EM1;
                float e7 = e6 * u;
                union { v8s v; unsigned dw[4]; } A;
                A.dw[0] = cvt_pk_bf16(e0, e1);
                A.dw[1] = cvt_pk_bf16(e2, e3);
                A.dw[2] = cvt_pk_bf16(e4, e5);
                A.dw[3] = cvt_pk_bf16(e6, e7);
                #pragma unroll
                for (int n = 0; n < 4; n++) C1[m][n] = MFMA(A.v, B1[kt][n], C1[m][n]);
            }
        }
    }

    // ssp -> bf16 -> swizzled LDS tile (row=edge, col=j1)
    #pragma unroll
    for (int m = 0; m < 4; m++)
        #pragma unroll
        for (int n = 0; n < 4; n++)
            #pragma unroll
            for (int i = 0; i < 4; i++) {
                int row = m*16 + (l>>4)*4 + i;
                int col = n*16 + colb;
                float v = ssp_f(C1[m][n][i] + b1v[n]);
                *(ushort_t*)(T + row*128 + ((col*2) ^ ((row&7)<<4))) = f2bf(v);
            }
    WAVE_BAR();

    // layer 2: hid @ w2
    v4f C2[4][4];
    #pragma unroll
    for (int m = 0; m < 4; m++)
        #pragma unroll
        for (int n = 0; n < 4; n++) C2[m][n] = (v4f){0,0,0,0};
    {
        v8s B2[2][4];
        #pragma unroll
        for (int n = 0; n < 4; n++)
            #pragma unroll
            for (int kt = 0; kt < 2; kt++)
                B2[kt][n] = *(const v8s*)(w2T + (n*16 + colb)*64 + kt*32 + krow);

        #pragma unroll
        for (int m = 0; m < 4; m++) {
            int row = m*16 + colb;
            #pragma unroll
            for (int kt = 0; kt < 2; kt++) {
                v8s a = *(const v8s*)(T + row*128 + ((kt*64 + krow*2) ^ ((row&7)<<4)));
                #pragma unroll
                for (int n = 0; n < 4; n++) C2[m][n] = MFMA(a, B2[kt][n], C2[m][n]);
            }
        }
    }
    WAVE_BAR();   // all layer-2 reads precede the W overwrite below (WAR)

    // W = (C2 + b2) * Cc -> f16 -> same tile.  Cc folded HERE (f32, per-row
    // via shfl) so the scatter loop carries no cc bookkeeping.
    #pragma unroll
    for (int m = 0; m < 4; m++)
        #pragma unroll
        for (int i = 0; i < 4; i++) {
            int row = m*16 + (l>>4)*4 + i;
            float ccr = __shfl(Cc, row);
            #pragma unroll
            for (int n = 0; n < 4; n++) {
                int col = n*16 + colb;
                *(ushort_t*)(T + row*128 + ((col*2) ^ ((row&7)<<4))) =
                    f2h((C2[m][n][i] + b2v[n]) * ccr);
            }
        }
    WAVE_BAR();

    // ---- scatter, split-phase, minimal per-iteration VALU ----
    // Phase 1: all h16 gathers (32-bit byte offsets on a common base) + all
    // LDS W-reads into named registers (statically indexed).
    int jj = l & 31;
    int hsel = l >> 5;                        // 0: even edge, 1: odd edge
    unsigned jj4 = (unsigned)jj * 4u;         // dword byte offset within row
    const char* h16b = (const char*)h16;
    unsigned hreg[32], wreg[32];
    #pragma unroll
    for (int e2 = 0; e2 < 32; e2++) {
        int sA = __builtin_amdgcn_readlane(s, 2*e2);
        int sB = __builtin_amdgcn_readlane(s, 2*e2 + 1);
        int ssel = hsel ? sB : sA;
        hreg[e2] = *(const unsigned*)(h16b + ((unsigned)ssel << 7) + jj4);
        int epair = 2*e2 + hsel;
        wreg[e2] = *(const unsigned*)(T + epair*128 + (jj4 ^ ((epair&7)<<4)));
    }
    // Phase 2: pure atomic stream — register data, common base + 32-bit
    // offset, fire-and-forget.
    char* aggb = (char*)agg16;
    #pragma unroll
    for (int e2 = 0; e2 < 32; e2++) {
        int dA = __builtin_amdgcn_readlane(d, 2*e2);
        int dB = __builtin_amdgcn_readlane(d, 2*e2 + 1);
        int dsel = hsel ? dB : dA;
        __half2 wv = __builtin_bit_cast(__half2, wreg[e2]);
        __half2 hv = __builtin_bit_cast(__half2, hreg[e2]);
        __half2 prod = __hmul2(wv, hv);
        unsafeAtomicAdd((__half2*)(aggb + ((unsigned)dsel << 7) + jj4), prod);
    }
}

// ---------- fused tail, MFMA, wave = 32 rows ----------
extern "C" __global__ __launch_bounds__(256)
void k_tail_mfma(const float* __restrict__ x, const ushort_t* __restrict__ agg16,
                 const ushort_t* __restrict__ w2cT, const float* __restrict__ b2c,
                 const ushort_t* __restrict__ wiT,  const float* __restrict__ bi,
                 const ushort_t* __restrict__ wlT,  const float* __restrict__ bl,
                 float* __restrict__ out, int N)
{
    __shared__ __align__(16) char lds[4][32*256];   // per-wave 32x128 bf16, XOR-swizzled
    int l = threadIdx.x & 63, w = threadIdx.x >> 6;
    char* T = lds[w];
    int base = (blockIdx.x * 4 + w) * 32;
    int colb = l & 15, krow = (l >> 4) * 8;

    float b2cv[8], biv[8], blv[8];
    #pragma unroll
    for (int n = 0; n < 8; n++) {
        b2cv[n] = b2c[n*16 + colb];
        biv[n]  = bi[n*16 + colb];
        blv[n]  = bl[n*16 + colb];
    }

    // stage A: agg[32,64](f16) @ w2cT(f16) -> ssp -> LDS  (f16 MFMA, no convert)
    v4f C[2][8];
    #pragma unroll
    for (int m = 0; m < 2; m++)
        #pragma unroll
        for (int n = 0; n < 8; n++) C[m][n] = (v4f){0,0,0,0};

    #pragma unroll
    for (int kt = 0; kt < 2; kt++) {
        v8h am[2];
        #pragma unroll
        for (int m = 0; m < 2; m++) {
            int row = base + m*16 + colb;
            v8h a = (v8h){0,0,0,0,0,0,0,0};
            if (row < N) a = *(const v8h*)(agg16 + (size_t)row*NF + kt*32 + krow);
            am[m] = a;
        }
        #pragma unroll
        for (int n = 0; n < 8; n++) {
            v8h b = *(const v8h*)(w2cT + (n*16 + colb)*64 + kt*32 + krow);
            #pragma unroll
            for (int m = 0; m < 2; m++) C[m][n] = MFMAH(am[m], b, C[m][n]);
        }
    }
    #pragma unroll
    for (int m = 0; m < 2; m++)
        #pragma unroll
        for (int n = 0; n < 8; n++)
            #pragma unroll
            for (int i = 0; i < 4; i++) {
                int rl = m*16 + (l>>4)*4 + i;
                int col = n*16 + colb;
                float v = ssp_f(C[m][n][i] + b2cv[n]);
                *(ushort_t*)(T + rl*256 + ((col*2) ^ ((rl&7)<<4))) = f2bf(v);
            }
    WAVE_BAR();

    // stage B: h2[32,128] @ wiT
    v4f D[2][8];
    #pragma unroll
    for (int m = 0; m < 2; m++)
        #pragma unroll
        for (int n = 0; n < 8; n++) D[m][n] = (v4f){0,0,0,0};

    v8s af[2][4];
    #pragma unroll
    for (int m = 0; m < 2; m++)
        #pragma unroll
        for (int kt = 0; kt < 4; kt++) {
            int rl = m*16 + colb;
            af[m][kt] = *(const v8s*)(T + rl*256 + ((kt*64 + krow*2) ^ ((rl&7)<<4)));
        }
    #pragma unroll
    for (int kt = 0; kt < 4; kt++)
        #pragma unroll
        for (int n = 0; n < 8; n++) {
            v8s b = *(const v8s*)(wiT + (n*16 + colb)*DIM + kt*32 + krow);
            #pragma unroll
            for (int m = 0; m < 2; m++) D[m][n] = MFMA(af[m][kt], b, D[m][n]);
        }
    WAVE_BAR();
    #pragma unroll
    for (int m = 0; m < 2; m++)
        #pragma unroll
        for (int n = 0; n < 8; n++)
            #pragma unroll
            for (int i = 0; i < 4; i++) {
                int rl = m*16 + (l>>4)*4 + i;
                int col = n*16 + colb;
                *(ushort_t*)(T + rl*256 + ((col*2) ^ ((rl&7)<<4))) = f2bf(D[m][n][i] + biv[n]);
            }
    WAVE_BAR();

    // stage C: h3[32,128] @ wlT -> relu -> +x -> out
    v4f G[2][8];
    #pragma unroll
    for (int m = 0; m < 2; m++)
        #pragma unroll
        for (int n = 0; n < 8; n++) G[m][n] = (v4f){0,0,0,0};

    #pragma unroll
    for (int m = 0; m < 2; m++)
        #pragma unroll
        for (int kt = 0; kt < 4; kt++) {
            int rl = m*16 + colb;
            af[m][kt] = *(const v8s*)(T + rl*256 + ((kt*64 + krow*2) ^ ((rl&7)<<4)));
        }
    #pragma unroll
    for (int kt = 0; kt < 4; kt++)
        #pragma unroll
        for (int n = 0; n < 8; n++) {
            v8s b = *(const v8s*)(wlT + (n*16 + colb)*DIM + kt*32 + krow);
            #pragma unroll
            for (int m = 0; m < 2; m++) G[m][n] = MFMA(af[m][kt], b, G[m][n]);
        }

    #pragma unroll
    for (int m = 0; m < 2; m++)
        #pragma unroll
        for (int n = 0; n < 8; n++)
            #pragma unroll
            for (int i = 0; i < 4; i++) {
                int row = base + m*16 + (l>>4)*4 + i;
                if (row < N) {
                    int col = n*16 + colb;
                    size_t o = (size_t)row*DIM + col;
                    out[o] = x[o] + fmaxf(G[m][n][i] + blv[n], 0.0f);
                }
            }
}

extern "C" void kernel_launch(void* const* d_in, const int* in_sizes, int n_in,
                              void* d_out, int out_size, void* d_ws, size_t ws_size,
                              hipStream_t stream)
{
    const float* x    = (const float*)d_in[0];
    const float* pos  = (const float*)d_in[1];
    const int*   ei   = (const int*)  d_in[2];
    const float* mw1  = (const float*)d_in[3];
    const float* mb1  = (const float*)d_in[4];
    const float* mw2  = (const float*)d_in[5];
    const float* mb2  = (const float*)d_in[6];
    const float* cl1  = (const float*)d_in[7];
    const float* cl2  = (const float*)d_in[8];
    const float* cl2b = (const float*)d_in[9];
    const float* iw   = (const float*)d_in[10];
    const float* ib   = (const float*)d_in[11];
    const float* lw   = (const float*)d_in[12];
    const float* lb   = (const float*)d_in[13];
    float* out = (float*)d_out;

    int N = in_sizes[0] / DIM;
    int E = in_sizes[2] / 2;

    char* W = (char*)d_ws;
    size_t h_bytes   = (size_t)N * NF * sizeof(ushort_t);
    size_t agg_bytes = (size_t)N * NF * sizeof(ushort_t);
    ushort_t* h16   = (ushort_t*)W;
    ushort_t* agg16 = (ushort_t*)(W + h_bytes);
    ushort_t* wT    = (ushort_t*)(W + h_bytes + agg_bytes);
    ushort_t* w1T  = wT;
    ushort_t* w2T  = wT + 4096;
    ushort_t* cl1T = wT + 8192;
    ushort_t* w2cT = wT + 16384;
    ushort_t* wiT  = wT + 24576;
    ushort_t* wlT  = wT + 40960;

    k_prep<<<60, 256, 0, stream>>>(mw1, mw2, cl1, cl2, iw, lw,
                                   w1T, w2T, cl1T, w2cT, wiT, wlT);

    k_lin1_mfma<<<(N + 127) / 128, 256, 0, stream>>>(x, cl1T, h16, agg16, N);

    int ewaves = (E + 63) / 64;
    k_edge_mfma<<<(ewaves + 3) / 4, 256, 0, stream>>>(pos, ei, h16, w1T, w2T,
                                                      mb1, mb2, agg16, E);

    k_tail_mfma<<<(N + 127) / 128, 256, 0, stream>>>(x, agg16, w2cT, cl2b,
                                                     wiT, ib, wlT, lb, out, N);
}